// Round 6
// baseline (658.619 us; speedup 1.0000x reference)
//
#include <hip/hip_runtime.h>
#include <float.h>

// ---------------- counting-sort + gather-reduce multi-aggregation ----------------
// Round-6 = round-5 with the nontemporal int4 compile fix (clang ext_vector v4i).
//   * hist_rank / scatter_rank: 4 edges/thread (32B dst loads, v4i rank I/O)
//   * reduce: 8 nodes per 512-thread block, float4-lane gather
//   * zero_counts vectorized
// ws layout (ints): counts[N] | lofs[N] | partials[512] | perm[E] | rank[E]

#define BLK 256
#define RBLK 512

typedef float v4f __attribute__((ext_vector_type(4)));
typedef int   v4i __attribute__((ext_vector_type(4)));

__device__ __forceinline__ v4f fmax4(v4f a, v4f b) {
    v4f r;
    r.x = fmaxf(a.x, b.x); r.y = fmaxf(a.y, b.y);
    r.z = fmaxf(a.z, b.z); r.w = fmaxf(a.w, b.w);
    return r;
}

__global__ void zero_counts(int* __restrict__ counts, int N) {
    int i = blockIdx.x * BLK + threadIdx.x;
    int n4 = N >> 2;
    if (i < n4) ((v4i*)counts)[i] = (v4i){0, 0, 0, 0};
    if (i < (N & 3)) counts[(n4 << 2) + i] = 0;       // tail (block 0)
}

// ---- rank path: one atomic pass, 4 edges/thread ----
__global__ void hist_rank(const int* __restrict__ dst, int stride,
                          int* __restrict__ counts, int* __restrict__ rank, int E) {
    int g = blockIdx.x * BLK + threadIdx.x;           // 4-edge group
    int ng = E >> 2;
    if (g < ng) {
        int n0, n1, n2, n3;
        if (stride == 2) {
            v4i a = ((const v4i*)dst)[2 * g];
            v4i b = ((const v4i*)dst)[2 * g + 1];
            n0 = a.x; n1 = a.z; n2 = b.x; n3 = b.z;
        } else {
            v4i a = ((const v4i*)dst)[g];
            n0 = a.x; n1 = a.y; n2 = a.z; n3 = a.w;
        }
        int r0 = atomicAdd(&counts[n0], 1);
        int r1 = atomicAdd(&counts[n1], 1);
        int r2 = atomicAdd(&counts[n2], 1);
        int r3 = atomicAdd(&counts[n3], 1);
        v4i rv = {r0, r1, r2, r3};
        __builtin_nontemporal_store(rv, (v4i*)rank + g);
    }
    if (g < (E & 3)) {                                // tail edges (block 0)
        int e = (ng << 2) + g;
        int n = (stride == 2) ? (int)((const long long*)dst)[e] : dst[e];
        rank[e] = atomicAdd(&counts[n], 1);
    }
}

__global__ void scatter_rank(const int* __restrict__ dst, int stride,
                             const int* __restrict__ lofs, const int* __restrict__ partials,
                             const int* __restrict__ rank, int* __restrict__ perm, int E) {
    int g = blockIdx.x * BLK + threadIdx.x;
    int ng = E >> 2;
    if (g < ng) {
        int n0, n1, n2, n3;
        if (stride == 2) {
            v4i a = ((const v4i*)dst)[2 * g];
            v4i b = ((const v4i*)dst)[2 * g + 1];
            n0 = a.x; n1 = a.z; n2 = b.x; n3 = b.z;
        } else {
            v4i a = ((const v4i*)dst)[g];
            n0 = a.x; n1 = a.y; n2 = a.z; n3 = a.w;
        }
        v4i r = __builtin_nontemporal_load((const v4i*)rank + g);
        int e = 4 * g;
        perm[lofs[n0] + partials[n0 >> 8] + r.x] = e;       // atomic-free
        perm[lofs[n1] + partials[n1 >> 8] + r.y] = e + 1;
        perm[lofs[n2] + partials[n2 >> 8] + r.z] = e + 2;
        perm[lofs[n3] + partials[n3 >> 8] + r.w] = e + 3;
    }
    if (g < (E & 3)) {
        int e = (ng << 2) + g;
        int n = (stride == 2) ? (int)((const long long*)dst)[e] : dst[e];
        perm[lofs[n] + partials[n >> 8] + rank[e]] = e;
    }
}

// ---- scans (unchanged) ----
__global__ void scan1(const int* __restrict__ counts, int* __restrict__ lofs,
                      int* __restrict__ partials, int N) {
    __shared__ int s[BLK];
    int t = threadIdx.x;
    int i = blockIdx.x * BLK + t;
    int x = (i < N) ? counts[i] : 0;
    s[t] = x;
    __syncthreads();
    for (int o = 1; o < BLK; o <<= 1) {
        int y = (t >= o) ? s[t - o] : 0;
        __syncthreads();
        s[t] += y;
        __syncthreads();
    }
    if (i < N) lofs[i] = s[t] - x;             // exclusive within chunk
    if (t == BLK - 1) partials[blockIdx.x] = s[t];
}

__global__ void scan2(int* __restrict__ partials, int NB) {
    __shared__ int s[512];
    int t = threadIdx.x;
    int x = (t < NB) ? partials[t] : 0;
    s[t] = x;
    __syncthreads();
    for (int o = 1; o < 512; o <<= 1) {
        int y = (t >= o) ? s[t - o] : 0;
        __syncthreads();
        s[t] += y;
        __syncthreads();
    }
    if (t < NB) partials[t] = s[t] - x;        // exclusive
}

// ---- fallback path (two atomic passes; only if ws too small for rank[E]) ----
__global__ void hist(const int* __restrict__ dst, int stride, int* __restrict__ counts, int E) {
    int e = blockIdx.x * BLK + threadIdx.x;
    if (e < E) {
        int n = (stride == 2) ? (int)((const long long*)dst)[e] : dst[e];
        atomicAdd(&counts[n], 1);
    }
}

__global__ void cursor_init(const int* __restrict__ lofs, const int* __restrict__ partials,
                            int* __restrict__ cursor, int N) {
    int i = blockIdx.x * BLK + threadIdx.x;
    if (i < N) cursor[i] = lofs[i] + partials[i >> 8];
}

__global__ void permscatter(const int* __restrict__ dst, int stride,
                            int* __restrict__ cursor, int* __restrict__ perm, int E) {
    int e = blockIdx.x * BLK + threadIdx.x;
    if (e < E) {
        int n = (stride == 2) ? (int)((const long long*)dst)[e] : dst[e];
        int pos = atomicAdd(&cursor[n], 1);
        perm[pos] = e;
    }
}

// ---- gather-reduce: one wave per node, 8 nodes per 512-thread block ----
// qid = lane>>4 selects one of 4 edges per group; fq = lane&15 selects the
// 16B feature quad. One VMEM instruction gathers 4 full rows (1KB) per wave.
__global__ void __launch_bounds__(RBLK) reduce(
        const float* __restrict__ msg, const int* __restrict__ perm,
        const int* __restrict__ lofs, const int* __restrict__ partials,
        const int* __restrict__ counts, float* __restrict__ out, int N) {
    int node = blockIdx.x * 8 + (threadIdx.x >> 6);
    if (node >= N) return;
    int lane = threadIdx.x & 63;
    int qid  = lane >> 4;          // edge slot 0..3 within a 4-edge group
    int fq   = lane & 15;          // feature quad (features 4*fq .. 4*fq+3)

    int beg   = lofs[node] + partials[node >> 8];
    int deg_i = counts[node];
    int end   = beg + deg_i;

    v4f s4 = {0.f, 0.f, 0.f, 0.f};
    v4f q4 = {0.f, 0.f, 0.f, 0.f};
    v4f m4 = {-FLT_MAX, -FLT_MAX, -FLT_MAX, -FLT_MAX};

    const v4f* __restrict__ msg4 = (const v4f*)msg;

    for (int base = beg; base < end; base += 64) {
        int cnt = end - base;
        if (cnt > 64) cnt = 64;
        int idx = base + lane;
        if (idx >= end) idx = end - 1;          // clamp: wave-uniform loop bound
        int eid_l = __builtin_nontemporal_load(perm + idx);

        int j = 0;
        for (; j + 8 <= cnt; j += 8) {
            int ea = __shfl(eid_l, j + qid);
            int eb = __shfl(eid_l, j + 4 + qid);
            v4f va = __builtin_nontemporal_load(msg4 + (((long long)ea << 4) + fq));
            v4f vb = __builtin_nontemporal_load(msg4 + (((long long)eb << 4) + fq));
            s4 += va; q4 += va * va; m4 = fmax4(m4, va);
            s4 += vb; q4 += vb * vb; m4 = fmax4(m4, vb);
        }
        int rem = cnt - j;                       // 0..7 edges left
        if (rem > 0) {
            int sa = j + qid;
            int ea = __shfl(eid_l, (sa < cnt) ? sa : (cnt - 1));
            v4f va = __builtin_nontemporal_load(msg4 + (((long long)ea << 4) + fq));
            if (sa < cnt) { s4 += va; q4 += va * va; m4 = fmax4(m4, va); }
            if (rem > 4) {
                int sb = j + 4 + qid;
                int eb = __shfl(eid_l, (sb < cnt) ? sb : (cnt - 1));
                v4f vb = __builtin_nontemporal_load(msg4 + (((long long)eb << 4) + fq));
                if (sb < cnt) { s4 += vb; q4 += vb * vb; m4 = fmax4(m4, vb); }
            }
        }
    }

    // fold the 4 edge-slots: butterfly over lane bits 4 and 5
    #pragma unroll
    for (int off = 16; off <= 32; off <<= 1) {
        s4.x += __shfl_xor(s4.x, off); s4.y += __shfl_xor(s4.y, off);
        s4.z += __shfl_xor(s4.z, off); s4.w += __shfl_xor(s4.w, off);
        q4.x += __shfl_xor(q4.x, off); q4.y += __shfl_xor(q4.y, off);
        q4.z += __shfl_xor(q4.z, off); q4.w += __shfl_xor(q4.w, off);
        m4.x = fmaxf(m4.x, __shfl_xor(m4.x, off));
        m4.y = fmaxf(m4.y, __shfl_xor(m4.y, off));
        m4.z = fmaxf(m4.z, __shfl_xor(m4.z, off));
        m4.w = fmaxf(m4.w, __shfl_xor(m4.w, off));
    }

    if (qid == 0) {                              // lanes 0..15 hold the totals
        float deg = fmaxf((float)deg_i, 1.0f);
        v4f mean = s4 / deg;
        v4f var  = q4 / deg - mean * mean;
        var.x = fmaxf(var.x, 0.f); var.y = fmaxf(var.y, 0.f);
        var.z = fmaxf(var.z, 0.f); var.w = fmaxf(var.w, 0.f);
        v4f stdv;
        stdv.x = sqrtf(var.x + 1e-8f); stdv.y = sqrtf(var.y + 1e-8f);
        stdv.z = sqrtf(var.z + 1e-8f); stdv.w = sqrtf(var.w + 1e-8f);
        v4f mx = m4;
        if (deg_i == 0) { mx.x = 0.f; mx.y = 0.f; mx.z = 0.f; mx.w = 0.f; }

        v4f* bo = (v4f*)(out + (long long)node * 256);
        __builtin_nontemporal_store(s4,   bo + fq);        // sum
        __builtin_nontemporal_store(mean, bo + 16 + fq);   // mean
        __builtin_nontemporal_store(mx,   bo + 32 + fq);   // max
        __builtin_nontemporal_store(stdv, bo + 48 + fq);   // std
    }
}

extern "C" void kernel_launch(void* const* d_in, const int* in_sizes, int n_in,
                              void* d_out, int out_size, void* d_ws, size_t ws_size,
                              hipStream_t stream) {
    const float* msg = (const float*)d_in[0];
    const int*   dst = (const int*)d_in[1];
    float* out = (float*)d_out;

    int E = in_sizes[0] / 64;                 // 1,600,000
    int N = out_size / 256;                   // 100,000
    int stride = (in_sizes[1] == 2 * E) ? 2 : 1;   // int64-as-int32-pairs defense

    int* counts   = (int*)d_ws;
    int* lofs     = counts + N;
    int* partials = lofs + N;                 // 512
    int* perm     = partials + 512;           // E
    int* extra    = perm + E;                 // rank[E] (rank path) or cursor[N] (fallback)

    int NB_N = (N + BLK - 1) / BLK;           // 391 (<= 512 required for scan2)
    int NB_E = (E + BLK - 1) / BLK;
    int NB_Z = ((N >> 2) + BLK - 1) / BLK;    // zero_counts (v4i)
    int NB_G = ((E >> 2) + BLK - 1) / BLK;    // 4-edge groups

    size_t need_rank = ((size_t)2 * N + 512 + (size_t)2 * E) * sizeof(int);

    zero_counts<<<NB_Z, BLK, 0, stream>>>(counts, N);

    if (ws_size >= need_rank) {
        // ---- single-atomic-pass counting sort ----
        int* rank = extra;
        hist_rank<<<NB_G, BLK, 0, stream>>>(dst, stride, counts, rank, E);
        scan1<<<NB_N, BLK, 0, stream>>>(counts, lofs, partials, N);
        scan2<<<1, 512, 0, stream>>>(partials, NB_N);
        scatter_rank<<<NB_G, BLK, 0, stream>>>(dst, stride, lofs, partials, rank, perm, E);
    } else {
        // ---- fallback: two-atomic-pass path ----
        int* cursor = extra;
        hist<<<NB_E, BLK, 0, stream>>>(dst, stride, counts, E);
        scan1<<<NB_N, BLK, 0, stream>>>(counts, lofs, partials, N);
        scan2<<<1, 512, 0, stream>>>(partials, NB_N);
        cursor_init<<<NB_N, BLK, 0, stream>>>(lofs, partials, cursor, N);
        permscatter<<<NB_E, BLK, 0, stream>>>(dst, stride, cursor, perm, E);
    }

    reduce<<<(N + 7) / 8, RBLK, 0, stream>>>(msg, perm, lofs, partials, counts, out, N);
}